// Round 6
// baseline (197.249 us; speedup 1.0000x reference)
//
#include <hip/hip_runtime.h>

// CenterLoss: loss = (1/B) * sum_j [ sum_{i: l_i=j} ||f_i - c_j||^2 / (n_j * D) ]
//           = (1/B) * sum_i d_i / (n_{l_i} * D)        (per-sample form, used here)
// B=65536, D=512, C=1000, fp32 in / fp32 scalar out. Memory-bound:
// 128 MiB features + 2 MiB centers + 0.25 MiB labels -> roofline ~21 us @ 6.3 TB/s.
//
// v7 = v6 with the compile fix: __builtin_nontemporal_load needs a clang
// ext_vector_type pointer, not HIP_vector_type (float4 struct). Otherwise
// identical to v6: (1) dist uses 1024-thread blocks (16 waves) -> 4096 blocks,
// partials 16KB; (2) features loaded non-temporally (read-once 128MiB stream,
// keep L2/L3 for centers+histT); (3) tail reduce is 16KB. Transposed histogram
// histT[class][64] read as one coalesced 256B wave-load, count reduced in the
// same butterfly as the distance, scale fused, no global atomics, no memsets.

#define WAVE 64
#define NCOL 64             // histogram columns == wavefront size (fixed)
#define HPAD 1024           // padded class count (nclass=1000 <= HPAD)
#define DWAVES 16           // waves per dist block (1024 threads)

typedef float fvec4 __attribute__((ext_vector_type(4)));   // nontemporal-compatible

// K1: 64 blocks; block b LDS-histograms its slab of labels, spills column b of
// the transposed histogram. Buffer fully overwritten -> no zeroing needed.
__global__ __launch_bounds__(256) void hist_kernel(
    const int* __restrict__ labels,       // [batch]
    unsigned int* __restrict__ histT,     // [HPAD][NCOL]
    int batch, int nclass, int slab)
{
    __shared__ unsigned int h[HPAD];
    for (int j = threadIdx.x; j < HPAD; j += 256) h[j] = 0u;
    __syncthreads();

    const int b  = blockIdx.x;            // 0..NCOL-1
    const int lo = b * slab;
    int hi = lo + slab; if (hi > batch) hi = batch;
    for (int i = lo + threadIdx.x; i < hi; i += 256)
        atomicAdd(&h[labels[i]], 1u);     // LDS atomic: cheap
    __syncthreads();

    for (int j = threadIdx.x; j < nclass; j += 256)
        histT[(size_t)j * NCOL + b] = h[j];
}

// K2: one wave per sample, 16 waves per block. Lanes cooperatively load the
// sample row (non-temporal: read-once stream) + its center row (cached) as
// 16B vectors; lane l also loads histT[label][l] (one coalesced 256B read per
// wave). Distance and count butterfly-reduced together; lane 0 forms
// d/(n*feat); block combines 16 waves -> 1 partial.
__global__ __launch_bounds__(1024) void center_dist_kernel(
    const float* __restrict__ features,   // [batch, feat]
    const float* __restrict__ centers,    // [nclass, feat]
    const int*   __restrict__ labels,     // [batch]
    const unsigned int* __restrict__ histT, // [HPAD][NCOL]
    float* __restrict__ partials,         // [gridDim.x]
    int batch, int feat)
{
    const int wib    = threadIdx.x >> 6;  // 0..15
    const int lane   = threadIdx.x & 63;
    const int sample = blockIdx.x * DWAVES + wib;

    __shared__ float wsum[DWAVES];
    float term = 0.0f;

    if (sample < batch) {
        const int label = labels[sample];

        // count column load: L2/L3-hot 256KB table, issue early
        unsigned int nl = histT[(size_t)label * NCOL + lane];

        const fvec4* __restrict__ f4 =
            (const fvec4*)(features + (size_t)sample * feat);
        const fvec4* __restrict__ c4 =
            (const fvec4*)(centers + (size_t)label * feat);

        float acc = 0.0f;
        const int n4 = feat >> 2;         // 128 for feat=512
#pragma unroll 2
        for (int idx = lane; idx < n4; idx += WAVE) {
            fvec4 fv = __builtin_nontemporal_load(&f4[idx]);  // stream, no reuse
            fvec4 cv = c4[idx];                               // cached (2MiB set)
            fvec4 d  = fv - cv;
            acc += d.x * d.x + d.y * d.y;
            acc += d.z * d.z + d.w * d.w;
        }

        int n = (int)nl;
#pragma unroll
        for (int off = 32; off > 0; off >>= 1) {
            acc += __shfl_down(acc, off, WAVE);
            n   += __shfl_down(n,   off, WAVE);
        }
        // lane 0 holds full sums; n >= 1 guaranteed (this sample has label l)
        term = acc / ((float)n * (float)feat);
    }

    if (lane == 0) wsum[wib] = term;
    __syncthreads();
    if (threadIdx.x == 0) {
        float s = 0.0f;
#pragma unroll
        for (int w = 0; w < DWAVES; ++w) s += wsum[w];
        partials[blockIdx.x] = s;
    }
}

// K3: single block, 1024 threads: reduce the 4096 block partials (16 KB,
// coalesced) -> loss scalar.
__global__ __launch_bounds__(1024) void reduce_kernel(
    const float* __restrict__ partials, float* __restrict__ out,
    int n, int batch)
{
    float acc = 0.0f;
#pragma unroll 4
    for (int i = threadIdx.x; i < n; i += 1024)
        acc += partials[i];

#pragma unroll
    for (int off = 32; off > 0; off >>= 1)
        acc += __shfl_down(acc, off, WAVE);

    __shared__ float warp_part[16];
    const int lane = threadIdx.x & 63;
    const int wid  = threadIdx.x >> 6;
    if (lane == 0) warp_part[wid] = acc;
    __syncthreads();

    if (threadIdx.x < WAVE) {
        float v = (threadIdx.x < 16) ? warp_part[threadIdx.x] : 0.0f;
#pragma unroll
        for (int off = 8; off > 0; off >>= 1)
            v += __shfl_down(v, off, WAVE);
        if (threadIdx.x == 0) out[0] = v / (float)batch;
    }
}

extern "C" void kernel_launch(void* const* d_in, const int* in_sizes, int n_in,
                              void* d_out, int out_size, void* d_ws, size_t ws_size,
                              hipStream_t stream) {
    const float* features = (const float*)d_in[0];
    const float* centers  = (const float*)d_in[1];
    const int*   labels   = (const int*)d_in[2];

    const int batch  = in_sizes[2];                 // 65536
    const int feat   = in_sizes[0] / batch;         // 512
    const int nclass = in_sizes[1] / feat;          // 1000

    const int slab        = (batch + NCOL - 1) / NCOL;          // 1024
    const int dist_blocks = (batch + DWAVES - 1) / DWAVES;      // 4096

    // Workspace layout (all fully overwritten -> no memset):
    //   histT    [HPAD][NCOL]  u32   256 KB
    //   partials [dist_blocks] f32    16 KB
    unsigned int* histT    = (unsigned int*)d_ws;
    float*        partials = (float*)(histT + (size_t)HPAD * NCOL);

    hist_kernel<<<NCOL, 256, 0, stream>>>(labels, histT, batch, nclass, slab);

    center_dist_kernel<<<dist_blocks, 1024, 0, stream>>>(
        features, centers, labels, histT, partials, batch, feat);

    reduce_kernel<<<1, 1024, 0, stream>>>(partials, (float*)d_out,
                                          dist_blocks, batch);
}